// Round 1
// baseline (700.571 us; speedup 1.0000x reference)
//
#include <hip/hip_runtime.h>
#include <stdint.h>

#define N_EDGES 2000000
#define NUM_SEG 500000
#define HID 128
#define NBLK 4

typedef __attribute__((ext_vector_type(8))) unsigned short ushort8;
typedef __attribute__((ext_vector_type(8))) __bf16 bf16x8;
typedef __attribute__((ext_vector_type(4))) float float4v;
typedef __attribute__((ext_vector_type(2))) uint32_t uint2v;

__device__ inline unsigned short f32_to_bf16(float f) {
    return __builtin_bit_cast(unsigned short, (__bf16)f);   // native cvt, RNE
}

__device__ inline uint32_t pack_bf16(float lo, float hi) {
#if __has_builtin(__builtin_amdgcn_cvt_pk_bf16_f32)
    typedef __attribute__((ext_vector_type(2))) __bf16 bf16x2;
    bf16x2 r = __builtin_amdgcn_cvt_pk_bf16_f32(lo, hi);
    return __builtin_bit_cast(uint32_t, r);
#else
    return (uint32_t)f32_to_bf16(lo) | ((uint32_t)f32_to_bf16(hi) << 16);
#endif
}

// ---- prep: WbF[blk] = bf16(W_res*rms_w) in A-FRAGMENT ORDER:
//   i = blk*16384 + (kt*8+ft)*512 + lane*8 + j -> W'[m=ft*16+(lane&15)][k=kt*32+(lane>>4)*8+j]
// Also packs Win4[f] = {W_in[f][0..2], b_in[f]} and zero-fills segsum.
__global__ void prep_kernel(const float* __restrict__ W_res,
                            const float* __restrict__ rms_w,
                            const float* __restrict__ W_in,
                            const float* __restrict__ b_in,
                            unsigned short* __restrict__ WbF,
                            float* __restrict__ Win4,
                            float* __restrict__ segsum) {
    int i = blockIdx.x * 256 + threadIdx.x;
    if (i < 65536) {
        int blk = i >> 14;
        int r = i & 16383;
        int j = r & 7, lane = (r >> 3) & 63, ft = (r >> 9) & 7, kt = r >> 12;
        int cc = lane & 15, qq = lane >> 4;
        int row = ft * 16 + cc;
        int k = kt * 32 + qq * 8 + j;
        WbF[i] = f32_to_bf16(W_res[blk * 16384 + row * HID + k] * rms_w[blk * HID + k]);
    } else if (i < 65536 + 128) {
        int f = i - 65536;
        Win4[f * 4 + 0] = W_in[f * 3 + 0];
        Win4[f * 4 + 1] = W_in[f * 3 + 1];
        Win4[f * 4 + 2] = W_in[f * 3 + 2];
        Win4[f * 4 + 3] = b_in[f];
    } else {
        int s = i - 65536 - 128;
        if (s < NUM_SEG) segsum[s] = 0.0f;
    }
}

// ---- fused MLP: 128 rows/wg, 4 waves x 32 rows.
// R1 change vs baseline: W staged in LDS in kt-HALVES (16 KB single buffer) instead
// of the full 32 KB per block. LDS/block 69,120 -> 52,736 B => 3 blocks/CU resident
// (12 waves/CU) instead of 2 (8 waves/CU). 4 barriers/blk, but every vmcnt drain at
// a barrier is covered: half-1 W prefetch flies under the kt01 MFMA phase, next-blk
// half-0 prefetch flies under the kt23 MFMA + epilogue. Per-row DS/VMEM/VALU work
// is unchanged -- this round isolates the occupancy/overlap variable.
__launch_bounds__(256, 3)
__global__ void mlp_kernel(const float* __restrict__ x,           // [N,3]
                           const unsigned short* __restrict__ WbF,// [4,16384] bf16 A-frag order
                           const float* __restrict__ b_res,       // [4,128]
                           const float* __restrict__ W_out,       // [128]
                           const float* __restrict__ b_out,       // [1]
                           const float* __restrict__ Win4g,       // [128,4] = {w0,w1,w2,b_in}
                           float* __restrict__ e) {               // [N] = exp(logit)
    __shared__ __align__(16) unsigned short WsF[8192];    // 16 KB: ONE kt-half of W (16 frags)
    __shared__ __align__(16) unsigned short hnF[16384];   // 32 KB, B-frag order (8KB/wave)
    __shared__ __align__(16) float4v Win4[128];
    __shared__ float xs[384];

    const int t = threadIdx.x;
    const int wave = t >> 6;
    const int lane = t & 63;
    const int q = lane >> 4;   // quad within wave
    const int c = lane & 15;   // lane within quad
    const long rowbase = (long)blockIdx.x * 128;

    // prefetch W half0 of blk 0 (lane-linear), 16 VGPRs; drained at B1, covered by stage-1
    ushort8 wreg[4];
    #pragma unroll
    for (int i = 0; i < 4; ++i)
        wreg[i] = *(const ushort8*)&WbF[(i * 256 + t) * 8];

    for (int i = t; i < 384; i += 256) xs[i] = x[rowbase * 3 + i];
    if (t < 128) Win4[t] = ((const float4v*)Win4g)[t];
    __syncthreads();

    // ---- stage 1: h0[f][r] = W_in[f].x[r] + b_in[f], straight into D-layout regs
    float4v h[8][2];   // [ft][rt], component = reg
    {
        float xr[2][3];
        #pragma unroll
        for (int rt = 0; rt < 2; ++rt)
            #pragma unroll
            for (int k = 0; k < 3; ++k)
                xr[rt][k] = xs[(wave * 32 + rt * 16 + c) * 3 + k];
        #pragma unroll
        for (int ft = 0; ft < 8; ++ft)
            #pragma unroll
            for (int reg = 0; reg < 4; ++reg) {
                float4v wb = Win4[ft * 16 + q * 4 + reg];
                #pragma unroll
                for (int rt = 0; rt < 2; ++rt)
                    h[ft][rt][reg] = wb.w + xr[rt][0] * wb.x + xr[rt][1] * wb.y + xr[rt][2] * wb.z;
            }
    }

    // hnF write base (shorts): frag(rt, kt=ft>>1), lane_d = ((ft&1)*2+(q>>1))*16+c, j=(q&1)*4+reg
    const int wbase = wave * 4096 + (q >> 1) * 128 + c * 8 + (q & 1) * 4;
    const int rbase = wave * 4096 + lane * 8;   // B-frag read base (lane-linear)
    const float4v zero4 = {0.0f, 0.0f, 0.0f, 0.0f};

    // ---- residual blocks
    for (int blk = 0; blk < NBLK; ++blk) {
        __syncthreads();   // B1: prev kt23 A-frag reads done; drains this blk's half0 prefetch
                           //     (covered by prev MFMA kt23 + epilogue / stage-1)
        // publish half0 (kt = 0,1)
        #pragma unroll
        for (int i = 0; i < 4; ++i)
            *(ushort8*)&WsF[(i * 256 + t) * 8] = wreg[i];

        // write raw h as packed bf16 into B-frag-order LDS (wave-local, 16 x ds_write_b64)
        #pragma unroll
        for (int ft = 0; ft < 8; ++ft) {
            const int foff = (ft >> 1) * 1024 + (ft & 1) * 256;
            #pragma unroll
            for (int rt = 0; rt < 2; ++rt) {
                uint2v v;
                v.x = pack_bf16(h[ft][rt][0], h[ft][rt][1]);
                v.y = pack_bf16(h[ft][rt][2], h[ft][rt][3]);
                *(uint2v*)&hnF[wbase + foff + rt * 512] = v;
            }
        }

        // rmsnorm scale per row (row = rt*16+c; in-lane over ft,reg then xor over q)
        float rs[2];
        #pragma unroll
        for (int rt = 0; rt < 2; ++rt) {
            float ss = 0.0f;
            #pragma unroll
            for (int ft = 0; ft < 8; ++ft) {
                #pragma unroll
                for (int reg = 0; reg < 4; ++reg) {
                    float vv = h[ft][rt][reg];
                    ss += vv * vv;
                }
            }
            ss += __shfl_xor(ss, 16, 64);
            ss += __shfl_xor(ss, 32, 64);
            rs[rt] = rsqrtf(ss * (1.0f / 128.0f) + 1.1920929e-7f);
        }

        __syncthreads();   // B2: half0 visible to all waves

        // prefetch half1 (kt = 2,3) -- in flight under the kt01 MFMA phase
        {
            const unsigned short* Wh = WbF + blk * 16384 + 8192;
            #pragma unroll
            for (int i = 0; i < 4; ++i)
                wreg[i] = *(const ushort8*)&Wh[(i * 256 + t) * 8];
        }

        // MFMA kt = 0,1 (A-frags: local 0..15 in WsF), kt=0 peeled (C=0)
        float4v acc[8][2];
        {
            bf16x8 b0 = __builtin_bit_cast(bf16x8, *(const ushort8*)&hnF[rbase + 0 * 512]);
            bf16x8 b1 = __builtin_bit_cast(bf16x8, *(const ushort8*)&hnF[rbase + 1 * 512]);
            #pragma unroll
            for (int ft = 0; ft < 8; ++ft) {
                bf16x8 a = __builtin_bit_cast(bf16x8, *(const ushort8*)&WsF[lane * 8 + ft * 512]);
                acc[ft][0] = __builtin_amdgcn_mfma_f32_16x16x32_bf16(a, b0, zero4, 0, 0, 0);
                acc[ft][1] = __builtin_amdgcn_mfma_f32_16x16x32_bf16(a, b1, zero4, 0, 0, 0);
            }
            b0 = __builtin_bit_cast(bf16x8, *(const ushort8*)&hnF[rbase + 2 * 512]);
            b1 = __builtin_bit_cast(bf16x8, *(const ushort8*)&hnF[rbase + 3 * 512]);
            #pragma unroll
            for (int ft = 0; ft < 8; ++ft) {
                bf16x8 a = __builtin_bit_cast(bf16x8,
                    *(const ushort8*)&WsF[lane * 8 + (8 + ft) * 512]);
                acc[ft][0] = __builtin_amdgcn_mfma_f32_16x16x32_bf16(a, b0, acc[ft][0], 0, 0, 0);
                acc[ft][1] = __builtin_amdgcn_mfma_f32_16x16x32_bf16(a, b1, acc[ft][1], 0, 0, 0);
            }
        }

        __syncthreads();   // B3: all waves done reading half0 (drains half1 prefetch -- covered)
        // publish half1 (kt = 2,3)
        #pragma unroll
        for (int i = 0; i < 4; ++i)
            *(ushort8*)&WsF[(i * 256 + t) * 8] = wreg[i];
        __syncthreads();   // B4: half1 visible

        // prefetch next blk half0 -- in flight under the kt23 MFMA phase + epilogue
        if (blk < NBLK - 1) {
            const unsigned short* Wn = WbF + (blk + 1) * 16384;
            #pragma unroll
            for (int i = 0; i < 4; ++i)
                wreg[i] = *(const ushort8*)&Wn[(i * 256 + t) * 8];
        }

        // MFMA kt = 2,3 (A-frags: local 0..15 in WsF again)
        {
            bf16x8 b0 = __builtin_bit_cast(bf16x8, *(const ushort8*)&hnF[rbase + 4 * 512]);
            bf16x8 b1 = __builtin_bit_cast(bf16x8, *(const ushort8*)&hnF[rbase + 5 * 512]);
            #pragma unroll
            for (int ft = 0; ft < 8; ++ft) {
                bf16x8 a = __builtin_bit_cast(bf16x8, *(const ushort8*)&WsF[lane * 8 + ft * 512]);
                acc[ft][0] = __builtin_amdgcn_mfma_f32_16x16x32_bf16(a, b0, acc[ft][0], 0, 0, 0);
                acc[ft][1] = __builtin_amdgcn_mfma_f32_16x16x32_bf16(a, b1, acc[ft][1], 0, 0, 0);
            }
            b0 = __builtin_bit_cast(bf16x8, *(const ushort8*)&hnF[rbase + 6 * 512]);
            b1 = __builtin_bit_cast(bf16x8, *(const ushort8*)&hnF[rbase + 7 * 512]);
            #pragma unroll
            for (int ft = 0; ft < 8; ++ft) {
                bf16x8 a = __builtin_bit_cast(bf16x8,
                    *(const ushort8*)&WsF[lane * 8 + (8 + ft) * 512]);
                acc[ft][0] = __builtin_amdgcn_mfma_f32_16x16x32_bf16(a, b0, acc[ft][0], 0, 0, 0);
                acc[ft][1] = __builtin_amdgcn_mfma_f32_16x16x32_bf16(a, b1, acc[ft][1], 0, 0, 0);
            }
        }

        // epilogue: h += relu(rs[rt]*acc + b_res[f])
        const float4v* br4 = (const float4v*)(b_res + blk * HID);
        #pragma unroll
        for (int ft = 0; ft < 8; ++ft) {
            float4v bb = br4[ft * 4 + q];
            #pragma unroll
            for (int rt = 0; rt < 2; ++rt) {
                #pragma unroll
                for (int reg = 0; reg < 4; ++reg)
                    h[ft][rt][reg] += fmaxf(fmaf(rs[rt], acc[ft][rt][reg], bb[reg]), 0.0f);
            }
        }
        // next iteration's B1 provides the "all waves done reading half1" barrier
    }

    // ---- output head: e[r] = exp(h[.][r] . W_out + b_out)
    const float bo = b_out[0];
    const float4v* wo4 = (const float4v*)W_out;
    float s[2] = {0.0f, 0.0f};
    #pragma unroll
    for (int ft = 0; ft < 8; ++ft) {
        float4v w = wo4[ft * 4 + q];
        #pragma unroll
        for (int rt = 0; rt < 2; ++rt) {
            #pragma unroll
            for (int reg = 0; reg < 4; ++reg)
                s[rt] += h[ft][rt][reg] * w[reg];
        }
    }
    #pragma unroll
    for (int rt = 0; rt < 2; ++rt) {
        s[rt] += __shfl_xor(s[rt], 16, 64);
        s[rt] += __shfl_xor(s[rt], 32, 64);
    }
    if (q == 0) {
        #pragma unroll
        for (int rt = 0; rt < 2; ++rt)
            e[rowbase + wave * 32 + rt * 16 + c] = __expf(s[rt] + bo);
    }
}

// ---- segment sum of e (sorted ids): wave-level segmented scan, tail lanes atomicAdd
__global__ void segsum_kernel(const float* __restrict__ e, const int* __restrict__ ids,
                              float* __restrict__ segsum) {
    int i = blockIdx.x * 256 + threadIdx.x;
    int lane = threadIdx.x & 63;
    float v = 0.0f; int id = -1;
    if (i < N_EDGES) { v = e[i]; id = ids[i]; }
    #pragma unroll
    for (int d = 1; d < 64; d <<= 1) {
        float ov = __shfl_up(v, d, 64);
        int oid = __shfl_up(id, d, 64);
        if (lane >= d && oid == id) v += ov;
    }
    int nid = __shfl_down(id, 1, 64);
    bool tail = (lane == 63) || (nid != id);
    if (id >= 0 && tail) atomicAdd(&segsum[id], v);
}

__global__ void norm_kernel(const float* __restrict__ e, const int* __restrict__ ids,
                            const float* __restrict__ segsum, float* __restrict__ out) {
    int i = blockIdx.x * 256 + threadIdx.x;
    if (i < N_EDGES) out[i] = e[i] / segsum[ids[i]];
}

extern "C" void kernel_launch(void* const* d_in, const int* in_sizes, int n_in,
                              void* d_out, int out_size, void* d_ws, size_t ws_size,
                              hipStream_t stream) {
    const float* x      = (const float*)d_in[0];
    const int*   ids    = (const int*)d_in[1];
    const float* W_in   = (const float*)d_in[2];
    const float* b_in   = (const float*)d_in[3];
    const float* rms_w  = (const float*)d_in[4];
    const float* W_res  = (const float*)d_in[5];
    const float* b_res  = (const float*)d_in[6];
    const float* W_out  = (const float*)d_in[7];
    const float* b_out  = (const float*)d_in[8];
    float* out = (float*)d_out;

    char* ws = (char*)d_ws;
    unsigned short* WbF = (unsigned short*)ws;                 // 131072 B
    float* Win4   = (float*)(ws + 131072);                     // 2048 B
    float* e      = (float*)(ws + 131072 + 2048);              // 8,000,000 B
    float* segsum = (float*)(ws + 131072 + 2048 + 8000000);    // 2,000,000 B

    int prep_items = 65536 + 128 + NUM_SEG;
    prep_kernel<<<(prep_items + 255) / 256, 256, 0, stream>>>(W_res, rms_w, W_in, b_in,
                                                              WbF, Win4, segsum);
    mlp_kernel<<<N_EDGES / 128, 256, 0, stream>>>(x, WbF, b_res, W_out, b_out, Win4, e);
    segsum_kernel<<<(N_EDGES + 255) / 256, 256, 0, stream>>>(e, ids, segsum);
    norm_kernel<<<(N_EDGES + 255) / 256, 256, 0, stream>>>(e, ids, segsum, out);
}

// Round 2
// 551.387 us; speedup vs baseline: 1.2706x; 1.2706x over previous
//
#include <hip/hip_runtime.h>
#include <stdint.h>

#define N_EDGES 2000000
#define NUM_SEG 500000
#define HID 128
#define NBLK 4

typedef __attribute__((ext_vector_type(8))) unsigned short ushort8;
typedef __attribute__((ext_vector_type(8))) __bf16 bf16x8;
typedef __attribute__((ext_vector_type(4))) float float4v;
typedef __attribute__((ext_vector_type(2))) uint32_t uint2v;

__device__ inline unsigned short f32_to_bf16(float f) {
    return __builtin_bit_cast(unsigned short, (__bf16)f);   // native cvt, RNE
}

__device__ inline uint32_t pack_bf16(float lo, float hi) {
#if __has_builtin(__builtin_amdgcn_cvt_pk_bf16_f32)
    typedef __attribute__((ext_vector_type(2))) __bf16 bf16x2;
    bf16x2 r = __builtin_amdgcn_cvt_pk_bf16_f32(lo, hi);
    return __builtin_bit_cast(uint32_t, r);
#else
    return (uint32_t)f32_to_bf16(lo) | ((uint32_t)f32_to_bf16(hi) << 16);
#endif
}

// ---- prep: WbF[blk] = bf16(W_res*rms_w) in A-FRAGMENT ORDER:
//   i = blk*16384 + (kt*8+ft)*512 + lane*8 + j -> W'[m=ft*16+(lane&15)][k=kt*32+(lane>>4)*8+j]
// Also packs Win4[f] = {W_in[f][0..2], b_in[f]} and zero-fills segsum.
__global__ void prep_kernel(const float* __restrict__ W_res,
                            const float* __restrict__ rms_w,
                            const float* __restrict__ W_in,
                            const float* __restrict__ b_in,
                            unsigned short* __restrict__ WbF,
                            float* __restrict__ Win4,
                            float* __restrict__ segsum) {
    int i = blockIdx.x * 256 + threadIdx.x;
    if (i < 65536) {
        int blk = i >> 14;
        int r = i & 16383;
        int j = r & 7, lane = (r >> 3) & 63, ft = (r >> 9) & 7, kt = r >> 12;
        int cc = lane & 15, qq = lane >> 4;
        int row = ft * 16 + cc;
        int k = kt * 32 + qq * 8 + j;
        WbF[i] = f32_to_bf16(W_res[blk * 16384 + row * HID + k] * rms_w[blk * HID + k]);
    } else if (i < 65536 + 128) {
        int f = i - 65536;
        Win4[f * 4 + 0] = W_in[f * 3 + 0];
        Win4[f * 4 + 1] = W_in[f * 3 + 1];
        Win4[f * 4 + 2] = W_in[f * 3 + 2];
        Win4[f * 4 + 3] = b_in[f];
    } else {
        int s = i - 65536 - 128;
        if (s < NUM_SEG) segsum[s] = 0.0f;
    }
}

// ---- fused MLP: 128 rows/wg, 4 waves x 32 rows.
// R2 change vs baseline: hnF is WAVE-PRIVATE (write base and read base are both
// wave-scoped) and its 8 B-fragments split cleanly by kt: frags for kt=0,1 come
// from ft=0..3, frags for kt=2,3 from ft=4..7. So stage it in TWO 4KB/wave halves
// reusing the same slots -- no extra barriers (DS ops are in-order within a wave).
// hnF 32KB -> 16KB; LDS/block 69,120 -> 52,736 => 3 blocks/CU (12 waves) instead
// of 2. W staging and launch_bounds(256,2) are EXACTLY the baseline (R1 showed a
// tighter reg cap spills ~69KB/wg to scratch; VGPR_Count must stay ~120).
__launch_bounds__(256, 2)
__global__ void mlp_kernel(const float* __restrict__ x,           // [N,3]
                           const unsigned short* __restrict__ WbF,// [4,16384] bf16 A-frag order
                           const float* __restrict__ b_res,       // [4,128]
                           const float* __restrict__ W_out,       // [128]
                           const float* __restrict__ b_out,       // [1]
                           const float* __restrict__ Win4g,       // [128,4] = {w0,w1,w2,b_in}
                           float* __restrict__ e) {               // [N] = exp(logit)
    __shared__ __align__(16) unsigned short WsF[16384];   // 32 KB, A-frag order (full block)
    __shared__ __align__(16) unsigned short hnF[8192];    // 16 KB, B-frag order (4KB/wave half)
    __shared__ __align__(16) float4v Win4[128];
    __shared__ float xs[384];

    const int t = threadIdx.x;
    const int wave = t >> 6;
    const int lane = t & 63;
    const int q = lane >> 4;   // quad within wave
    const int c = lane & 15;   // lane within quad
    const long rowbase = (long)blockIdx.x * 128;

    // prefetch W for blk 0 (lane-linear)
    ushort8 wreg[8];
    #pragma unroll
    for (int i = 0; i < 8; ++i)
        wreg[i] = *(const ushort8*)&WbF[(i * 256 + t) * 8];

    for (int i = t; i < 384; i += 256) xs[i] = x[rowbase * 3 + i];
    if (t < 128) Win4[t] = ((const float4v*)Win4g)[t];
    __syncthreads();

    // ---- stage 1: h0[f][r] = W_in[f].x[r] + b_in[f], straight into D-layout regs
    float4v h[8][2];   // [ft][rt], component = reg
    {
        float xr[2][3];
        #pragma unroll
        for (int rt = 0; rt < 2; ++rt)
            #pragma unroll
            for (int k = 0; k < 3; ++k)
                xr[rt][k] = xs[(wave * 32 + rt * 16 + c) * 3 + k];
        #pragma unroll
        for (int ft = 0; ft < 8; ++ft)
            #pragma unroll
            for (int reg = 0; reg < 4; ++reg) {
                float4v wb = Win4[ft * 16 + q * 4 + reg];
                #pragma unroll
                for (int rt = 0; rt < 2; ++rt)
                    h[ft][rt][reg] = wb.w + xr[rt][0] * wb.x + xr[rt][1] * wb.y + xr[rt][2] * wb.z;
            }
    }

    // hnF (halved) write base, shorts. Per half: slot = kt_local*2 + rt, 512 shorts/slot.
    // lane_d = ((ft&1)*2+(q>>1))*16+c, j=(q&1)*4+reg; kt_local = (ft>>1)&1
    const int wbase = wave * 2048 + (q >> 1) * 128 + c * 8 + (q & 1) * 4;
    const int rbase = wave * 2048 + lane * 8;   // B-frag read base (lane-linear)
    const float4v zero4 = {0.0f, 0.0f, 0.0f, 0.0f};

    // ---- residual blocks
    for (int blk = 0; blk < NBLK; ++blk) {
        // publish this block's W to LDS (lane-contiguous, conflict-free)
        #pragma unroll
        for (int i = 0; i < 8; ++i)
            *(ushort8*)&WsF[(i * 256 + t) * 8] = wreg[i];
        __syncthreads();
        // prefetch next block's W (in flight during MFMA)
        if (blk < NBLK - 1) {
            const unsigned short* Wn = WbF + (blk + 1) * 16384;
            #pragma unroll
            for (int i = 0; i < 8; ++i)
                wreg[i] = *(const ushort8*)&Wn[(i * 256 + t) * 8];
        }

        // half0: write ft=0..3 (frags for kt=0,1) as packed bf16 (8 x ds_write_b64)
        #pragma unroll
        for (int ft = 0; ft < 4; ++ft) {
            const int foff = ((ft >> 1) & 1) * 1024 + (ft & 1) * 256;
            #pragma unroll
            for (int rt = 0; rt < 2; ++rt) {
                uint2v v;
                v.x = pack_bf16(h[ft][rt][0], h[ft][rt][1]);
                v.y = pack_bf16(h[ft][rt][2], h[ft][rt][3]);
                *(uint2v*)&hnF[wbase + foff + rt * 512] = v;
            }
        }

        // rmsnorm scale per row (row = rt*16+c; in-lane over ft,reg then xor over q)
        float rs[2];
        #pragma unroll
        for (int rt = 0; rt < 2; ++rt) {
            float ss = 0.0f;
            #pragma unroll
            for (int ft = 0; ft < 8; ++ft) {
                #pragma unroll
                for (int reg = 0; reg < 4; ++reg) {
                    float vv = h[ft][rt][reg];
                    ss += vv * vv;
                }
            }
            ss += __shfl_xor(ss, 16, 64);
            ss += __shfl_xor(ss, 32, 64);
            rs[rt] = rsqrtf(ss * (1.0f / 128.0f) + 1.1920929e-7f);
        }

        // MFMA kt = 0,1 (reads half0 slots 0..3), kt=0 peeled (C=0)
        float4v acc[8][2];
        {
            bf16x8 b0 = __builtin_bit_cast(bf16x8, *(const ushort8*)&hnF[rbase + 0 * 512]);
            bf16x8 b1 = __builtin_bit_cast(bf16x8, *(const ushort8*)&hnF[rbase + 1 * 512]);
            #pragma unroll
            for (int ft = 0; ft < 8; ++ft) {
                bf16x8 a = __builtin_bit_cast(bf16x8, *(const ushort8*)&WsF[lane * 8 + ft * 512]);
                acc[ft][0] = __builtin_amdgcn_mfma_f32_16x16x32_bf16(a, b0, zero4, 0, 0, 0);
                acc[ft][1] = __builtin_amdgcn_mfma_f32_16x16x32_bf16(a, b1, zero4, 0, 0, 0);
            }
            b0 = __builtin_bit_cast(bf16x8, *(const ushort8*)&hnF[rbase + 2 * 512]);
            b1 = __builtin_bit_cast(bf16x8, *(const ushort8*)&hnF[rbase + 3 * 512]);
            #pragma unroll
            for (int ft = 0; ft < 8; ++ft) {
                bf16x8 a = __builtin_bit_cast(bf16x8,
                    *(const ushort8*)&WsF[lane * 8 + (8 + ft) * 512]);
                acc[ft][0] = __builtin_amdgcn_mfma_f32_16x16x32_bf16(a, b0, acc[ft][0], 0, 0, 0);
                acc[ft][1] = __builtin_amdgcn_mfma_f32_16x16x32_bf16(a, b1, acc[ft][1], 0, 0, 0);
            }
        }

        // half1: write ft=4..7 (frags for kt=2,3) into the SAME slots.
        // Wave-private + DS in-order => write-after-read hazard is handled by the
        // wave's own lgkmcnt ordering; no barrier needed.
        #pragma unroll
        for (int ft = 4; ft < 8; ++ft) {
            const int foff = ((ft >> 1) & 1) * 1024 + (ft & 1) * 256;
            #pragma unroll
            for (int rt = 0; rt < 2; ++rt) {
                uint2v v;
                v.x = pack_bf16(h[ft][rt][0], h[ft][rt][1]);
                v.y = pack_bf16(h[ft][rt][2], h[ft][rt][3]);
                *(uint2v*)&hnF[wbase + foff + rt * 512] = v;
            }
        }

        // MFMA kt = 2,3 (reads half1 in slots 0..3)
        {
            bf16x8 b0 = __builtin_bit_cast(bf16x8, *(const ushort8*)&hnF[rbase + 0 * 512]);
            bf16x8 b1 = __builtin_bit_cast(bf16x8, *(const ushort8*)&hnF[rbase + 1 * 512]);
            #pragma unroll
            for (int ft = 0; ft < 8; ++ft) {
                bf16x8 a = __builtin_bit_cast(bf16x8,
                    *(const ushort8*)&WsF[lane * 8 + (16 + ft) * 512]);
                acc[ft][0] = __builtin_amdgcn_mfma_f32_16x16x32_bf16(a, b0, acc[ft][0], 0, 0, 0);
                acc[ft][1] = __builtin_amdgcn_mfma_f32_16x16x32_bf16(a, b1, acc[ft][1], 0, 0, 0);
            }
            b0 = __builtin_bit_cast(bf16x8, *(const ushort8*)&hnF[rbase + 2 * 512]);
            b1 = __builtin_bit_cast(bf16x8, *(const ushort8*)&hnF[rbase + 3 * 512]);
            #pragma unroll
            for (int ft = 0; ft < 8; ++ft) {
                bf16x8 a = __builtin_bit_cast(bf16x8,
                    *(const ushort8*)&WsF[lane * 8 + (24 + ft) * 512]);
                acc[ft][0] = __builtin_amdgcn_mfma_f32_16x16x32_bf16(a, b0, acc[ft][0], 0, 0, 0);
                acc[ft][1] = __builtin_amdgcn_mfma_f32_16x16x32_bf16(a, b1, acc[ft][1], 0, 0, 0);
            }
        }

        // epilogue: h += relu(rs[rt]*acc + b_res[f])
        const float4v* br4 = (const float4v*)(b_res + blk * HID);
        #pragma unroll
        for (int ft = 0; ft < 8; ++ft) {
            float4v bb = br4[ft * 4 + q];
            #pragma unroll
            for (int rt = 0; rt < 2; ++rt) {
                #pragma unroll
                for (int reg = 0; reg < 4; ++reg)
                    h[ft][rt][reg] += fmaxf(fmaf(rs[rt], acc[ft][rt][reg], bb[reg]), 0.0f);
            }
        }
        __syncthreads();   // all waves done reading WsF before next publish
    }

    // ---- output head: e[r] = exp(h[.][r] . W_out + b_out)
    const float bo = b_out[0];
    const float4v* wo4 = (const float4v*)W_out;
    float s[2] = {0.0f, 0.0f};
    #pragma unroll
    for (int ft = 0; ft < 8; ++ft) {
        float4v w = wo4[ft * 4 + q];
        #pragma unroll
        for (int rt = 0; rt < 2; ++rt) {
            #pragma unroll
            for (int reg = 0; reg < 4; ++reg)
                s[rt] += h[ft][rt][reg] * w[reg];
        }
    }
    #pragma unroll
    for (int rt = 0; rt < 2; ++rt) {
        s[rt] += __shfl_xor(s[rt], 16, 64);
        s[rt] += __shfl_xor(s[rt], 32, 64);
    }
    if (q == 0) {
        #pragma unroll
        for (int rt = 0; rt < 2; ++rt)
            e[rowbase + wave * 32 + rt * 16 + c] = __expf(s[rt] + bo);
    }
}

// ---- segment sum of e (sorted ids): wave-level segmented scan, tail lanes atomicAdd
__global__ void segsum_kernel(const float* __restrict__ e, const int* __restrict__ ids,
                              float* __restrict__ segsum) {
    int i = blockIdx.x * 256 + threadIdx.x;
    int lane = threadIdx.x & 63;
    float v = 0.0f; int id = -1;
    if (i < N_EDGES) { v = e[i]; id = ids[i]; }
    #pragma unroll
    for (int d = 1; d < 64; d <<= 1) {
        float ov = __shfl_up(v, d, 64);
        int oid = __shfl_up(id, d, 64);
        if (lane >= d && oid == id) v += ov;
    }
    int nid = __shfl_down(id, 1, 64);
    bool tail = (lane == 63) || (nid != id);
    if (id >= 0 && tail) atomicAdd(&segsum[id], v);
}

__global__ void norm_kernel(const float* __restrict__ e, const int* __restrict__ ids,
                            const float* __restrict__ segsum, float* __restrict__ out) {
    int i = blockIdx.x * 256 + threadIdx.x;
    if (i < N_EDGES) out[i] = e[i] / segsum[ids[i]];
}

extern "C" void kernel_launch(void* const* d_in, const int* in_sizes, int n_in,
                              void* d_out, int out_size, void* d_ws, size_t ws_size,
                              hipStream_t stream) {
    const float* x      = (const float*)d_in[0];
    const int*   ids    = (const int*)d_in[1];
    const float* W_in   = (const float*)d_in[2];
    const float* b_in   = (const float*)d_in[3];
    const float* rms_w  = (const float*)d_in[4];
    const float* W_res  = (const float*)d_in[5];
    const float* b_res  = (const float*)d_in[6];
    const float* W_out  = (const float*)d_in[7];
    const float* b_out  = (const float*)d_in[8];
    float* out = (float*)d_out;

    char* ws = (char*)d_ws;
    unsigned short* WbF = (unsigned short*)ws;                 // 131072 B
    float* Win4   = (float*)(ws + 131072);                     // 2048 B
    float* e      = (float*)(ws + 131072 + 2048);              // 8,000,000 B
    float* segsum = (float*)(ws + 131072 + 2048 + 8000000);    // 2,000,000 B

    int prep_items = 65536 + 128 + NUM_SEG;
    prep_kernel<<<(prep_items + 255) / 256, 256, 0, stream>>>(W_res, rms_w, W_in, b_in,
                                                              WbF, Win4, segsum);
    mlp_kernel<<<N_EDGES / 128, 256, 0, stream>>>(x, WbF, b_res, W_out, b_out, Win4, e);
    segsum_kernel<<<(N_EDGES + 255) / 256, 256, 0, stream>>>(e, ids, segsum);
    norm_kernel<<<(N_EDGES + 255) / 256, 256, 0, stream>>>(e, ids, segsum, out);
}

// Round 3
// 540.876 us; speedup vs baseline: 1.2953x; 1.0194x over previous
//
#include <hip/hip_runtime.h>
#include <stdint.h>

#define N_EDGES 2000000
#define NUM_SEG 500000
#define HID 128
#define NBLK 4

typedef __attribute__((ext_vector_type(8))) unsigned short ushort8;
typedef __attribute__((ext_vector_type(8))) __bf16 bf16x8;
typedef __attribute__((ext_vector_type(4))) float float4v;
typedef __attribute__((ext_vector_type(2))) uint32_t uint2v;

__device__ inline unsigned short f32_to_bf16(float f) {
    return __builtin_bit_cast(unsigned short, (__bf16)f);   // native cvt, RNE
}

__device__ inline uint32_t pack_bf16(float lo, float hi) {
#if __has_builtin(__builtin_amdgcn_cvt_pk_bf16_f32)
    typedef __attribute__((ext_vector_type(2))) __bf16 bf16x2;
    bf16x2 r = __builtin_amdgcn_cvt_pk_bf16_f32(lo, hi);
    return __builtin_bit_cast(uint32_t, r);
#else
    return (uint32_t)f32_to_bf16(lo) | ((uint32_t)f32_to_bf16(hi) << 16);
#endif
}

// ---- prep: WbF[blk] = bf16(W_res*rms_w) in A-FRAGMENT ORDER:
//   i = blk*16384 + (kt*8+ft)*512 + lane*8 + j -> W'[m=ft*16+(lane&15)][k=kt*32+(lane>>4)*8+j]
// Also packs Win4[f] = {W_in[f][0..2], b_in[f]} and zero-fills segsum.
__global__ void prep_kernel(const float* __restrict__ W_res,
                            const float* __restrict__ rms_w,
                            const float* __restrict__ W_in,
                            const float* __restrict__ b_in,
                            unsigned short* __restrict__ WbF,
                            float* __restrict__ Win4,
                            float* __restrict__ segsum) {
    int i = blockIdx.x * 256 + threadIdx.x;
    if (i < 65536) {
        int blk = i >> 14;
        int r = i & 16383;
        int j = r & 7, lane = (r >> 3) & 63, ft = (r >> 9) & 7, kt = r >> 12;
        int cc = lane & 15, qq = lane >> 4;
        int row = ft * 16 + cc;
        int k = kt * 32 + qq * 8 + j;
        WbF[i] = f32_to_bf16(W_res[blk * 16384 + row * HID + k] * rms_w[blk * HID + k]);
    } else if (i < 65536 + 128) {
        int f = i - 65536;
        Win4[f * 4 + 0] = W_in[f * 3 + 0];
        Win4[f * 4 + 1] = W_in[f * 3 + 1];
        Win4[f * 4 + 2] = W_in[f * 3 + 2];
        Win4[f * 4 + 3] = b_in[f];
    } else {
        int s = i - 65536 - 128;
        if (s < NUM_SEG) segsum[s] = 0.0f;
    }
}

// ---- fused MLP: 128 rows/wg, 4 waves x 32 rows.
// R3: total LDS forced to exactly 32 KiB to make the occupancy increase granule-proof
// (R2 showed 52.7 KiB still gave only 2 blocks/CU -> coarse LDS allocation granule
// suspected). Cuts: (1) W staged in kt-HALVES, 16 KiB single buffer (R1 structure,
// which failed only because of its (256,3) reg cap -> 69KB/wg scratch; here we keep
// (256,2), wreg shrinks 32->16 VGPRs); (2) hnF halved to 16 KiB (R2, proven); (3)
// Win4/xs OVERLAY the hnF region (dead after stage-1, which completes before the
// first hnF write at the blk-0 barrier). 4 barriers/blk, every drain covered by an
// in-flight prefetch. VGPR must stay ~100 with zero scratch (FETCH ~12 MB tripwire).
__launch_bounds__(256, 2)
__global__ void mlp_kernel(const float* __restrict__ x,           // [N,3]
                           const unsigned short* __restrict__ WbF,// [4,16384] bf16 A-frag order
                           const float* __restrict__ b_res,       // [4,128]
                           const float* __restrict__ W_out,       // [128]
                           const float* __restrict__ b_out,       // [1]
                           const float* __restrict__ Win4g,       // [128,4] = {w0,w1,w2,b_in}
                           float* __restrict__ e) {               // [N] = exp(logit)
    __shared__ __align__(16) unsigned char smem[32768];
    unsigned short* WsF  = (unsigned short*)smem;            // 16,384 B: ONE kt-half of W
    unsigned short* hnF  = (unsigned short*)(smem + 16384);  // 16,384 B: B-frag halves (4KB/wave)
    float4v*        Win4 = (float4v*)(smem + 16384);         // overlay: 2,048 B (dead after stage-1)
    float*          xs   = (float*)(smem + 16384 + 2048);    // overlay: 1,536 B (dead after stage-1)

    const int t = threadIdx.x;
    const int wave = t >> 6;
    const int lane = t & 63;
    const int q = lane >> 4;   // quad within wave
    const int c = lane & 15;   // lane within quad
    const long rowbase = (long)blockIdx.x * 128;

    // prefetch W half0 of blk 0 (lane-linear), 16 VGPRs
    ushort8 wreg[4];
    #pragma unroll
    for (int i = 0; i < 4; ++i)
        wreg[i] = *(const ushort8*)&WbF[(i * 256 + t) * 8];

    for (int i = t; i < 384; i += 256) xs[i] = x[rowbase * 3 + i];
    if (t < 128) Win4[t] = ((const float4v*)Win4g)[t];
    __syncthreads();

    // ---- stage 1: h0[f][r] = W_in[f].x[r] + b_in[f], straight into D-layout regs
    float4v h[8][2];   // [ft][rt], component = reg
    {
        float xr[2][3];
        #pragma unroll
        for (int rt = 0; rt < 2; ++rt)
            #pragma unroll
            for (int k = 0; k < 3; ++k)
                xr[rt][k] = xs[(wave * 32 + rt * 16 + c) * 3 + k];
        #pragma unroll
        for (int ft = 0; ft < 8; ++ft)
            #pragma unroll
            for (int reg = 0; reg < 4; ++reg) {
                float4v wb = Win4[ft * 16 + q * 4 + reg];
                #pragma unroll
                for (int rt = 0; rt < 2; ++rt)
                    h[ft][rt][reg] = wb.w + xr[rt][0] * wb.x + xr[rt][1] * wb.y + xr[rt][2] * wb.z;
            }
    }

    // hnF (halved) bases, shorts. Slot layout identical to R2 (harness-verified).
    const int wbase = wave * 2048 + (q >> 1) * 128 + c * 8 + (q & 1) * 4;
    const int rbase = wave * 2048 + lane * 8;   // B-frag read base (lane-linear)
    const float4v zero4 = {0.0f, 0.0f, 0.0f, 0.0f};

    // ---- residual blocks
    for (int blk = 0; blk < NBLK; ++blk) {
        __syncthreads();   // B1: prev blk's kt23 A-reads done (blk0: stage-1 Win4/xs reads done)
        // publish W half0 (kt = 0,1) -- lane-contiguous, conflict-free
        #pragma unroll
        for (int i = 0; i < 4; ++i)
            *(ushort8*)&WsF[(i * 256 + t) * 8] = wreg[i];

        // write hn half0: ft=0..3 (frags for kt=0,1), packed bf16, 8 x ds_write_b64
        #pragma unroll
        for (int ft = 0; ft < 4; ++ft) {
            const int foff = ((ft >> 1) & 1) * 1024 + (ft & 1) * 256;
            #pragma unroll
            for (int rt = 0; rt < 2; ++rt) {
                uint2v v;
                v.x = pack_bf16(h[ft][rt][0], h[ft][rt][1]);
                v.y = pack_bf16(h[ft][rt][2], h[ft][rt][3]);
                *(uint2v*)&hnF[wbase + foff + rt * 512] = v;
            }
        }

        // rmsnorm scale per row (row = rt*16+c; in-lane over ft,reg then xor over q)
        float rs[2];
        #pragma unroll
        for (int rt = 0; rt < 2; ++rt) {
            float ss = 0.0f;
            #pragma unroll
            for (int ft = 0; ft < 8; ++ft) {
                #pragma unroll
                for (int reg = 0; reg < 4; ++reg) {
                    float vv = h[ft][rt][reg];
                    ss += vv * vv;
                }
            }
            ss += __shfl_xor(ss, 16, 64);
            ss += __shfl_xor(ss, 32, 64);
            rs[rt] = rsqrtf(ss * (1.0f / 128.0f) + 1.1920929e-7f);
        }

        __syncthreads();   // B2: W half0 visible to all waves

        // prefetch W half1 (kt = 2,3) -- flies under the kt01 MFMA phase
        {
            const unsigned short* Wh = WbF + blk * 16384 + 8192;
            #pragma unroll
            for (int i = 0; i < 4; ++i)
                wreg[i] = *(const ushort8*)&Wh[(i * 256 + t) * 8];
        }

        // MFMA kt = 0,1 (A local frags 0..15, B = hn half0 slots 0..3), kt=0 peeled (C=0)
        float4v acc[8][2];
        {
            bf16x8 b0 = __builtin_bit_cast(bf16x8, *(const ushort8*)&hnF[rbase + 0 * 512]);
            bf16x8 b1 = __builtin_bit_cast(bf16x8, *(const ushort8*)&hnF[rbase + 1 * 512]);
            #pragma unroll
            for (int ft = 0; ft < 8; ++ft) {
                bf16x8 a = __builtin_bit_cast(bf16x8, *(const ushort8*)&WsF[lane * 8 + ft * 512]);
                acc[ft][0] = __builtin_amdgcn_mfma_f32_16x16x32_bf16(a, b0, zero4, 0, 0, 0);
                acc[ft][1] = __builtin_amdgcn_mfma_f32_16x16x32_bf16(a, b1, zero4, 0, 0, 0);
            }
            b0 = __builtin_bit_cast(bf16x8, *(const ushort8*)&hnF[rbase + 2 * 512]);
            b1 = __builtin_bit_cast(bf16x8, *(const ushort8*)&hnF[rbase + 3 * 512]);
            #pragma unroll
            for (int ft = 0; ft < 8; ++ft) {
                bf16x8 a = __builtin_bit_cast(bf16x8,
                    *(const ushort8*)&WsF[lane * 8 + (8 + ft) * 512]);
                acc[ft][0] = __builtin_amdgcn_mfma_f32_16x16x32_bf16(a, b0, acc[ft][0], 0, 0, 0);
                acc[ft][1] = __builtin_amdgcn_mfma_f32_16x16x32_bf16(a, b1, acc[ft][1], 0, 0, 0);
            }
        }

        // write hn half1: ft=4..7 into the SAME slots. Wave-private + in-order DS =>
        // write-after-read ordering is the wave's own lgkmcnt; no barrier needed.
        #pragma unroll
        for (int ft = 4; ft < 8; ++ft) {
            const int foff = ((ft >> 1) & 1) * 1024 + (ft & 1) * 256;
            #pragma unroll
            for (int rt = 0; rt < 2; ++rt) {
                uint2v v;
                v.x = pack_bf16(h[ft][rt][0], h[ft][rt][1]);
                v.y = pack_bf16(h[ft][rt][2], h[ft][rt][3]);
                *(uint2v*)&hnF[wbase + foff + rt * 512] = v;
            }
        }

        __syncthreads();   // B3: all waves done with kt01 A-reads of WsF
        // publish W half1 (kt = 2,3)
        #pragma unroll
        for (int i = 0; i < 4; ++i)
            *(ushort8*)&WsF[(i * 256 + t) * 8] = wreg[i];
        __syncthreads();   // B4: W half1 visible

        // prefetch next blk's W half0 -- flies under the kt23 MFMA phase + epilogue
        if (blk < NBLK - 1) {
            const unsigned short* Wn = WbF + (blk + 1) * 16384;
            #pragma unroll
            for (int i = 0; i < 4; ++i)
                wreg[i] = *(const ushort8*)&Wn[(i * 256 + t) * 8];
        }

        // MFMA kt = 2,3 (A local frags 0..15 of half1, B = hn half1 in slots 0..3)
        {
            bf16x8 b0 = __builtin_bit_cast(bf16x8, *(const ushort8*)&hnF[rbase + 0 * 512]);
            bf16x8 b1 = __builtin_bit_cast(bf16x8, *(const ushort8*)&hnF[rbase + 1 * 512]);
            #pragma unroll
            for (int ft = 0; ft < 8; ++ft) {
                bf16x8 a = __builtin_bit_cast(bf16x8, *(const ushort8*)&WsF[lane * 8 + ft * 512]);
                acc[ft][0] = __builtin_amdgcn_mfma_f32_16x16x32_bf16(a, b0, acc[ft][0], 0, 0, 0);
                acc[ft][1] = __builtin_amdgcn_mfma_f32_16x16x32_bf16(a, b1, acc[ft][1], 0, 0, 0);
            }
            b0 = __builtin_bit_cast(bf16x8, *(const ushort8*)&hnF[rbase + 2 * 512]);
            b1 = __builtin_bit_cast(bf16x8, *(const ushort8*)&hnF[rbase + 3 * 512]);
            #pragma unroll
            for (int ft = 0; ft < 8; ++ft) {
                bf16x8 a = __builtin_bit_cast(bf16x8,
                    *(const ushort8*)&WsF[lane * 8 + (8 + ft) * 512]);
                acc[ft][0] = __builtin_amdgcn_mfma_f32_16x16x32_bf16(a, b0, acc[ft][0], 0, 0, 0);
                acc[ft][1] = __builtin_amdgcn_mfma_f32_16x16x32_bf16(a, b1, acc[ft][1], 0, 0, 0);
            }
        }

        // epilogue: h += relu(rs[rt]*acc + b_res[f])
        const float4v* br4 = (const float4v*)(b_res + blk * HID);
        #pragma unroll
        for (int ft = 0; ft < 8; ++ft) {
            float4v bb = br4[ft * 4 + q];
            #pragma unroll
            for (int rt = 0; rt < 2; ++rt) {
                #pragma unroll
                for (int reg = 0; reg < 4; ++reg)
                    h[ft][rt][reg] += fmaxf(fmaf(rs[rt], acc[ft][rt][reg], bb[reg]), 0.0f);
            }
        }
        // next iteration's B1 is the "all waves done reading W half1" barrier
    }

    // ---- output head: e[r] = exp(h[.][r] . W_out + b_out)
    const float bo = b_out[0];
    const float4v* wo4 = (const float4v*)W_out;
    float s[2] = {0.0f, 0.0f};
    #pragma unroll
    for (int ft = 0; ft < 8; ++ft) {
        float4v w = wo4[ft * 4 + q];
        #pragma unroll
        for (int rt = 0; rt < 2; ++rt) {
            #pragma unroll
            for (int reg = 0; reg < 4; ++reg)
                s[rt] += h[ft][rt][reg] * w[reg];
        }
    }
    #pragma unroll
    for (int rt = 0; rt < 2; ++rt) {
        s[rt] += __shfl_xor(s[rt], 16, 64);
        s[rt] += __shfl_xor(s[rt], 32, 64);
    }
    if (q == 0) {
        #pragma unroll
        for (int rt = 0; rt < 2; ++rt)
            e[rowbase + wave * 32 + rt * 16 + c] = __expf(s[rt] + bo);
    }
}

// ---- segment sum of e (sorted ids): wave-level segmented scan, tail lanes atomicAdd
__global__ void segsum_kernel(const float* __restrict__ e, const int* __restrict__ ids,
                              float* __restrict__ segsum) {
    int i = blockIdx.x * 256 + threadIdx.x;
    int lane = threadIdx.x & 63;
    float v = 0.0f; int id = -1;
    if (i < N_EDGES) { v = e[i]; id = ids[i]; }
    #pragma unroll
    for (int d = 1; d < 64; d <<= 1) {
        float ov = __shfl_up(v, d, 64);
        int oid = __shfl_up(id, d, 64);
        if (lane >= d && oid == id) v += ov;
    }
    int nid = __shfl_down(id, 1, 64);
    bool tail = (lane == 63) || (nid != id);
    if (id >= 0 && tail) atomicAdd(&segsum[id], v);
}

__global__ void norm_kernel(const float* __restrict__ e, const int* __restrict__ ids,
                            const float* __restrict__ segsum, float* __restrict__ out) {
    int i = blockIdx.x * 256 + threadIdx.x;
    if (i < N_EDGES) out[i] = e[i] / segsum[ids[i]];
}

extern "C" void kernel_launch(void* const* d_in, const int* in_sizes, int n_in,
                              void* d_out, int out_size, void* d_ws, size_t ws_size,
                              hipStream_t stream) {
    const float* x      = (const float*)d_in[0];
    const int*   ids    = (const int*)d_in[1];
    const float* W_in   = (const float*)d_in[2];
    const float* b_in   = (const float*)d_in[3];
    const float* rms_w  = (const float*)d_in[4];
    const float* W_res  = (const float*)d_in[5];
    const float* b_res  = (const float*)d_in[6];
    const float* W_out  = (const float*)d_in[7];
    const float* b_out  = (const float*)d_in[8];
    float* out = (float*)d_out;

    char* ws = (char*)d_ws;
    unsigned short* WbF = (unsigned short*)ws;                 // 131072 B
    float* Win4   = (float*)(ws + 131072);                     // 2048 B
    float* e      = (float*)(ws + 131072 + 2048);              // 8,000,000 B
    float* segsum = (float*)(ws + 131072 + 2048 + 8000000);    // 2,000,000 B

    int prep_items = 65536 + 128 + NUM_SEG;
    prep_kernel<<<(prep_items + 255) / 256, 256, 0, stream>>>(W_res, rms_w, W_in, b_in,
                                                              WbF, Win4, segsum);
    mlp_kernel<<<N_EDGES / 128, 256, 0, stream>>>(x, WbF, b_res, W_out, b_out, Win4, e);
    segsum_kernel<<<(N_EDGES + 255) / 256, 256, 0, stream>>>(e, ids, segsum);
    norm_kernel<<<(N_EDGES + 255) / 256, 256, 0, stream>>>(e, ids, segsum, out);
}